// Round 5
// baseline (4179.816 us; speedup 1.0000x reference)
//
#include <hip/hip_runtime.h>

#define NPOS 65536   // 64 batches * 32 * 32 positions
#define NE   121     // 11*11 tensor entries
#define NP   6       // p-rows per half for conv1x1 (P0 = ph*5; row 5 dup)
#define NPP  4       // p-rows per third for f0/conv3x3 (P0 = part*4; 4+4+3)

// ------------------------------------------------------------------
// f0: 8-channel 3x3 tensorized conv, 16x16 -> 11x11, writes raw y.
// Grid: 6144 = (b,h) x 3 p-parts; swizzle keeps a row's parts and
// h-neighbors on one XCD (x reuse in L2). Block: 256 thr = (c, w).
// Live regs: Y[4][11]=44 + A[4][4]=16 + Xr4 + addr ~ 85 -> no spill
// (R1-R4 lesson: allocator ceiling is 128 VGPRs; must fit UNDER it).
// ------------------------------------------------------------------
__global__ __launch_bounds__(256, 2)
void f0_kernel(const float* __restrict__ x, const float* __restrict__ U,
               const float* __restrict__ V, float* __restrict__ y) {
  __shared__ float smem[2816];                // su(512)+sv(1408); reduce reuses 2816
  int bid = blockIdx.x;
  int wg  = (bid & 7) * 768 + (bid >> 3);     // bijective, 6144 % 8 == 0
  int part = wg % 3;                          // p-part; parts of a row adjacent
  int row  = wg / 3;                          // (b,h)
  int b = row >> 5, h = row & 31;
  int P0 = part * 4;
  int pmax = (part == 2) ? 3 : 4;             // valid output rows this part
  int t = threadIdx.x;
  int c = t >> 5, w = t & 31;

  float* su = smem;           // [c][pr][m] : c*64 + pr*16 + m   (512)
  float* sv = smem + 512;     // [c][q][n]  : c*176 + q*16 + n   (1408)

  float Y[NPP][11];
#pragma unroll
  for (int p = 0; p < NPP; ++p)
#pragma unroll
    for (int q = 0; q < 11; ++q) Y[p][q] = 0.f;

  for (int ij = 0; ij < 9; ++ij) {
    __syncthreads();
    for (int idx = t; idx < 512; idx += 256) {
      int cc = idx >> 6, r = idx & 63;
      int pr = r >> 4, m = r & 15;
      int srow = P0 + pr; if (srow > 10) srow = 10;   // clamp (row 3 of part 2 = dup)
      su[idx] = U[(cc * 9 + ij) * 176 + srow * 16 + m];
    }
    for (int idx = t; idx < 1408; idx += 256) {
      int cc = idx / 176, qn = idx - cc * 176;
      sv[512 - 512 + 0 + idx] = V[(cc * 9 + ij) * 176 + qn];  // sv[idx]
    }
    __syncthreads();
    int i = ij / 3, j = ij - 3 * (ij / 3);
    int hi = h + i - 1, wj = w + j - 1;
    if ((unsigned)hi < 32u && (unsigned)wj < 32u) {
      const float* xb = x + ((size_t)(b * 8 + c) << 18) + (hi << 5) + wj;
      const float* uB = &su[c * 64];
      const float* vB = &sv[c * 176];
      for (int nc = 0; nc < 4; ++nc) {        // n in chunks of 4
        float A[NPP][4];
#pragma unroll
        for (int p = 0; p < NPP; ++p)
#pragma unroll
          for (int k = 0; k < 4; ++k) A[p][k] = 0.f;
#pragma unroll 2
        for (int m = 0; m < 16; ++m) {
          float Xr[4];
#pragma unroll
          for (int k = 0; k < 4; ++k)
            Xr[k] = xb[(m * 16 + nc * 4 + k) << 10];
#pragma unroll
          for (int p = 0; p < NPP; ++p) {
            float u = uB[p * 16 + m];
#pragma unroll
            for (int k = 0; k < 4; ++k) A[p][k] += u * Xr[k];
          }
        }
#pragma unroll
        for (int k = 0; k < 4; ++k) {
#pragma unroll
          for (int q = 0; q < 11; ++q) {
            float vv = vB[q * 16 + nc * 4 + k];
#pragma unroll
            for (int p = 0; p < NPP; ++p) Y[p][q] += A[p][k] * vv;
          }
        }
      }
    }
  }

  // reduce over c (8 threads per (w,q)) through LDS, one valid p-row at a time
  int posb = ((b << 5) + h) << 5;
  for (int p = 0; p < pmax; ++p) {            // pmax uniform per block
    __syncthreads();
#pragma unroll
    for (int q = 0; q < 11; ++q) smem[(c * 32 + w) * 11 + q] = Y[p][q];
    __syncthreads();
    for (int idx = t; idx < 352; idx += 256) {
      int qq = idx >> 5, w2 = idx & 31;
      float s = 0.f;
#pragma unroll
      for (int cc = 0; cc < 8; ++cc) s += smem[(cc * 32 + w2) * 11 + qq];
      y[(size_t)((P0 + p) * 11 + qq) * NPOS + posb + w2] = s;
    }
  }
}

// ------------------------------------------------------------------
// TBN stats: partial sums (484 blocks), then finalize scale/shift.
// ------------------------------------------------------------------
__global__ __launch_bounds__(256)
void stats_partial(const float* __restrict__ raw, float* __restrict__ part) {
  int blk = blockIdx.x;
  int e = blk >> 2, qt = blk & 3;
  const float4* p = (const float4*)(raw + (size_t)e * NPOS) + qt * 4096;
  int t = threadIdx.x;
  float s = 0.f, s2 = 0.f;
  for (int i = t; i < 4096; i += 256) {
    float4 v = p[i];
    s  += v.x + v.y + v.z + v.w;
    s2 += v.x * v.x + v.y * v.y + v.z * v.z + v.w * v.w;
  }
#pragma unroll
  for (int o = 32; o > 0; o >>= 1) {
    s  += __shfl_down(s, o);
    s2 += __shfl_down(s2, o);
  }
  __shared__ float ls[8];
  int wid = t >> 6;
  if ((t & 63) == 0) { ls[wid] = s; ls[4 + wid] = s2; }
  __syncthreads();
  if (t == 0) {
    part[blk]       = ls[0] + ls[1] + ls[2] + ls[3];
    part[484 + blk] = ls[4] + ls[5] + ls[6] + ls[7];
  }
}

__global__ void stats_final(const float* __restrict__ part, const float* __restrict__ g,
                            const float* __restrict__ bb, float* __restrict__ sc,
                            float* __restrict__ sh) {
  int e = threadIdx.x;
  if (e < 121) {
    float s  = part[e * 4] + part[e * 4 + 1] + part[e * 4 + 2] + part[e * 4 + 3];
    float s2 = part[484 + e * 4] + part[484 + e * 4 + 1] +
               part[484 + e * 4 + 2] + part[484 + e * 4 + 3];
    float mu  = s  * (1.f / 65536.f);
    float var = s2 * (1.f / 65536.f) - mu * mu;
    float sca = g[e] * rsqrtf(var + 1e-5f);
    sc[e] = sca;
    sh[e] = bb[e] - mu * sca;
  }
}

// ------------------------------------------------------------------
// tconv1x1: out_raw = U * hin * V^T per position, 2-way p-split.
// hin = affine(A) [+ affine(B)] [then PReLU(alpha)], applied on load.
// Grid: 512 = 256 pos-blocks x 2 halves. ~90 live regs -> fits 128.
// ------------------------------------------------------------------
template<bool HASB, bool PRELU>
__global__ __launch_bounds__(256, 2)
void conv1x1_kernel(const float* __restrict__ rA, const float* __restrict__ scA,
                    const float* __restrict__ shA,
                    const float* __restrict__ rB, const float* __restrict__ scB,
                    const float* __restrict__ shB,
                    const float* __restrict__ alpha_ptr, int alpha_idx,
                    const float* __restrict__ U, const float* __restrict__ V,
                    float* __restrict__ out) {
  __shared__ float su[NP * 11], sv[121], sa[242], sb[242];
  int bid = blockIdx.x;
  int wg  = (bid & 7) * 64 + (bid >> 3);      // 512 % 8 == 0, bijective
  int ph = wg & 1, posblk = wg >> 1;
  int P0 = ph * 5;
  int t = threadIdx.x;
  if (t < 121) {
    sv[t] = V[t];
    sa[t] = scA[t]; sb[t] = shA[t];
    if (HASB) { sa[121 + t] = scB[t]; sb[121 + t] = shB[t]; }
  }
  if (t < NP * 11) su[t] = U[P0 * 11 + t];    // su[pr*11+m] = U[(P0+pr)*11+m]
  __syncthreads();
  float alpha = 0.f;
  if (PRELU) alpha = alpha_ptr[alpha_idx];
  size_t pos = (size_t)posblk * 256 + t;

  float T[NP][11];
#pragma unroll
  for (int p = 0; p < NP; ++p)
#pragma unroll
    for (int n = 0; n < 11; ++n) T[p][n] = 0.f;

#pragma unroll 2
  for (int m = 0; m < 11; ++m) {
    float Xr[11];
#pragma unroll
    for (int n = 0; n < 11; ++n) {
      int e = m * 11 + n;
      float v = sa[e] * rA[(size_t)e * NPOS + pos] + sb[e];
      if (HASB) v += sa[121 + e] * rB[(size_t)e * NPOS + pos] + sb[121 + e];
      if (PRELU) v = v >= 0.f ? v : alpha * v;
      Xr[n] = v;
    }
#pragma unroll
    for (int p = 0; p < NP; ++p) {
      float u = su[p * 11 + m];
#pragma unroll
      for (int n = 0; n < 11; ++n) T[p][n] += u * Xr[n];
    }
  }
#pragma unroll
  for (int q = 0; q < 11; ++q) {
    float Yc[NP];
#pragma unroll
    for (int p = 0; p < NP; ++p) Yc[p] = 0.f;
#pragma unroll
    for (int n = 0; n < 11; ++n) {
      float v = sv[q * 11 + n];
#pragma unroll
      for (int p = 0; p < NP; ++p) Yc[p] += T[p][n] * v;
    }
#pragma unroll
    for (int p = 0; p < NP; ++p)
      out[(size_t)((P0 + p) * 11 + q) * NPOS + pos] = Yc[p];
  }
}

// ------------------------------------------------------------------
// tconv3x3, 3-way p-split. Grid: 768 = 256 pos-blocks x 3 parts.
// Y[4][11]=44 + T[4][4]=16 + Xr4 ≈ 80 live -> no spill.
// ------------------------------------------------------------------
template<int N0, int NW>
__device__ __forceinline__ void c3_chunk(const float* __restrict__ rA,
    const float* __restrict__ sa, const float* __restrict__ sh,
    const float* __restrict__ su, const float* __restrict__ sv,
    float alpha, int npos, float (&Y)[NPP][11]) {
  float T[NPP][NW];
#pragma unroll
  for (int p = 0; p < NPP; ++p)
#pragma unroll
    for (int k = 0; k < NW; ++k) T[p][k] = 0.f;
#pragma unroll 2
  for (int m = 0; m < 11; ++m) {
    float Xr[NW];
#pragma unroll
    for (int k = 0; k < NW; ++k) {
      int e = m * 11 + N0 + k;
      float v = sa[e] * rA[(size_t)e * NPOS + npos] + sh[e];
      Xr[k] = v >= 0.f ? v : alpha * v;
    }
#pragma unroll
    for (int p = 0; p < NPP; ++p) {
      float u = su[p * 11 + m];
#pragma unroll
      for (int k = 0; k < NW; ++k) T[p][k] += u * Xr[k];
    }
  }
#pragma unroll
  for (int k = 0; k < NW; ++k) {
#pragma unroll
    for (int q = 0; q < 11; ++q) {
      float v = sv[q * 11 + N0 + k];
#pragma unroll
      for (int p = 0; p < NPP; ++p) Y[p][q] += T[p][k] * v;
    }
  }
}

__global__ __launch_bounds__(256, 2)
void conv3x3_kernel(const float* __restrict__ rA, const float* __restrict__ scA,
                    const float* __restrict__ shA,
                    const float* __restrict__ alpha_ptr, int alpha_idx,
                    const float* __restrict__ U, const float* __restrict__ V,
                    float* __restrict__ out) {
  __shared__ float su[9 * NPP * 11], sv[1089], sa[121], sh[121];
  int bid = blockIdx.x;
  int wg  = (bid & 7) * 96 + (bid >> 3);      // 768 % 8 == 0
  int part = wg % 3, posblk = wg / 3;
  int P0 = part * 4;
  int pmax = (part == 2) ? 3 : 4;
  int t = threadIdx.x;
  for (int idx = t; idx < 9 * NPP * 11; idx += 256) {
    int ij = idx / (NPP * 11), r = idx - ij * (NPP * 11);   // r = pr*11+m
    int pr = r / 11, m = r - pr * 11;
    int srow = P0 + pr; if (srow > 10) srow = 10;           // clamp dup row
    su[idx] = U[ij * 121 + srow * 11 + m];
  }
  for (int idx = t; idx < 1089; idx += 256) sv[idx] = V[idx];
  if (t < 121) { sa[t] = scA[t]; sh[t] = shA[t]; }
  __syncthreads();
  float alpha = alpha_ptr[alpha_idx];
  int pos = posblk * 256 + t;
  int b = pos >> 10, h = (pos >> 5) & 31, w = pos & 31;

  float Y[NPP][11];
#pragma unroll
  for (int p = 0; p < NPP; ++p)
#pragma unroll
    for (int q = 0; q < 11; ++q) Y[p][q] = 0.f;

  for (int ij = 0; ij < 9; ++ij) {
    int i = ij / 3, j = ij - 3 * (ij / 3);
    int hi = h + i - 1, wj = w + j - 1;
    if ((unsigned)hi >= 32u || (unsigned)wj >= 32u) continue;  // zero pad: tap = 0
    int npos = ((b << 5) + hi) * 32 + wj;
    const float* suij = &su[ij * NPP * 11];
    const float* svij = &sv[ij * 121];
    c3_chunk<0, 4>(rA, sa, sh, suij, svij, alpha, npos, Y);
    c3_chunk<4, 4>(rA, sa, sh, suij, svij, alpha, npos, Y);
    c3_chunk<8, 3>(rA, sa, sh, suij, svij, alpha, npos, Y);
  }
  for (int p = 0; p < pmax; ++p)              // pmax uniform per block
#pragma unroll
    for (int q = 0; q < 11; ++q)
      out[(size_t)((P0 + p) * 11 + q) * NPOS + pos] = Y[p][q];
}

// ------------------------------------------------------------------
// fcn head: out[b,o,h,w] = sum_e h[e]*W[o,e]; h = affine(A)+affine(B).
// ------------------------------------------------------------------
__global__ __launch_bounds__(256, 2)
void head_kernel(const float* __restrict__ rA, const float* __restrict__ scA,
                 const float* __restrict__ shA,
                 const float* __restrict__ rB, const float* __restrict__ scB,
                 const float* __restrict__ shB,
                 const float* __restrict__ W, float* __restrict__ out) {
  __shared__ float sw[21 * 121], sa[242], sh[242];
  int t = threadIdx.x;
  for (int idx = t; idx < 2541; idx += 256) sw[idx] = W[idx];
  if (t < 121) {
    sa[t] = scA[t]; sh[t] = shA[t];
    sa[121 + t] = scB[t]; sh[121 + t] = shB[t];
  }
  __syncthreads();
  size_t pos = (size_t)blockIdx.x * 256 + t;
  int b = (int)(pos >> 10), hw = (int)(pos & 1023);
  float acc[21];
#pragma unroll
  for (int o = 0; o < 21; ++o) acc[o] = 0.f;
  for (int e = 0; e < 121; ++e) {
    float v = sa[e] * rA[(size_t)e * NPOS + pos] + sh[e] +
              sa[121 + e] * rB[(size_t)e * NPOS + pos] + sh[121 + e];
#pragma unroll
    for (int o = 0; o < 21; ++o) acc[o] += v * sw[o * 121 + e];
  }
#pragma unroll
  for (int o = 0; o < 21; ++o)
    out[(size_t)(b * 21 + o) * 1024 + hw] = acc[o];
}

// ------------------------------------------------------------------
extern "C" void kernel_launch(void* const* d_in, const int* in_sizes, int n_in,
                              void* d_out, int out_size, void* d_ws, size_t ws_size,
                              hipStream_t stream) {
  (void)in_sizes; (void)n_in; (void)out_size; (void)ws_size;
  const float* x     = (const float*)d_in[0];
  const float* f0_U  = (const float*)d_in[1];
  const float* f0_V  = (const float*)d_in[2];
  const float* f0_g  = (const float*)d_in[3];
  const float* f0_b  = (const float*)d_in[4];
  const float* f0_a  = (const float*)d_in[5];
  const float* s_U   = (const float*)d_in[6];
  const float* s_V   = (const float*)d_in[7];
  const float* s_g   = (const float*)d_in[8];
  const float* s_b   = (const float*)d_in[9];
  const float* bU1   = (const float*)d_in[10];
  const float* bV1   = (const float*)d_in[11];
  const float* bg1   = (const float*)d_in[12];
  const float* bb1   = (const float*)d_in[13];
  const float* ba1   = (const float*)d_in[14];
  const float* bU2   = (const float*)d_in[15];
  const float* bV2   = (const float*)d_in[16];
  const float* bg2   = (const float*)d_in[17];
  const float* bb2   = (const float*)d_in[18];
  const float* ba2   = (const float*)d_in[19];
  const float* bU3   = (const float*)d_in[20];
  const float* bV3   = (const float*)d_in[21];
  const float* bg3   = (const float*)d_in[22];
  const float* bb3   = (const float*)d_in[23];
  const float* headW = (const float*)d_in[24];

  float* ws = (float*)d_ws;
  const size_t BUF = (size_t)NE * NPOS;           // 7,929,856 floats per buffer
  float* B[4] = { ws, ws + BUF, ws + 2 * BUF, ws + 3 * BUF };
  float* st   = ws + 4 * BUF;                     // 17 ops * (scale121 + shift121)
  float* part = st + 17 * 242;                    // 968 floats of partial sums

  auto SCp = [&](int op) { return st + op * 242; };
  auto SHp = [&](int op) { return st + op * 242 + 121; };
  auto run_stats = [&](const float* raw, const float* g, const float* bb, int op) {
    stats_partial<<<484, 256, 0, stream>>>(raw, part);
    stats_final<<<1, 128, 0, stream>>>(part, g, bb, SCp(op), SHp(op));
  };

  // ---- f0 ----
  f0_kernel<<<6144, 256, 0, stream>>>(x, f0_U, f0_V, B[0]);
  run_stats(B[0], f0_g, f0_b, 0);

  // buffer rotation: for each block k -> {idn, z1, z2, z3} buffer index
  const int bufs[4][4] = { {1,2,3,0}, {2,3,0,1}, {3,0,1,2}, {0,1,2,3} };

  const float* hA   = B[0];  const float* hAsc = SCp(0); const float* hAsh = SHp(0);
  const float* hB   = nullptr; const float* hBsc = nullptr; const float* hBsh = nullptr;

  for (int k = 0; k < 4; ++k) {
    float* idn = B[bufs[k][0]];
    float* z1  = B[bufs[k][1]];
    float* z2  = B[bufs[k][2]];
    float* z3  = B[bufs[k][3]];
    int op_idn = 1 + k * 4, op_z1 = 2 + k * 4, op_z2 = 3 + k * 4, op_z3 = 4 + k * 4;

    if (k == 0) {  // h0 = prelu(tbn(y), f0_a): single source + prelu
      conv1x1_kernel<false, true><<<512, 256, 0, stream>>>(
          hA, hAsc, hAsh, nullptr, nullptr, nullptr, f0_a, 0,
          s_U + k * 121, s_V + k * 121, idn);
      conv1x1_kernel<false, true><<<512, 256, 0, stream>>>(
          hA, hAsc, hAsh, nullptr, nullptr, nullptr, f0_a, 0,
          bU1 + k * 121, bV1 + k * 121, z1);
    } else {       // h = tbn(z3_prev) + tbn(idn_prev): two sources, no prelu
      conv1x1_kernel<true, false><<<512, 256, 0, stream>>>(
          hA, hAsc, hAsh, hB, hBsc, hBsh, nullptr, 0,
          s_U + k * 121, s_V + k * 121, idn);
      conv1x1_kernel<true, false><<<512, 256, 0, stream>>>(
          hA, hAsc, hAsh, hB, hBsc, hBsh, nullptr, 0,
          bU1 + k * 121, bV1 + k * 121, z1);
    }
    run_stats(idn, s_g + k * 121, s_b + k * 121, op_idn);
    run_stats(z1,  bg1 + k * 121, bb1 + k * 121, op_z1);

    conv3x3_kernel<<<768, 256, 0, stream>>>(
        z1, SCp(op_z1), SHp(op_z1), ba1, k,
        bU2 + k * 1089, bV2 + k * 1089, z2);
    run_stats(z2, bg2 + k * 121, bb2 + k * 121, op_z2);

    conv1x1_kernel<false, true><<<512, 256, 0, stream>>>(
        z2, SCp(op_z2), SHp(op_z2), nullptr, nullptr, nullptr, ba2, k,
        bU3 + k * 121, bV3 + k * 121, z3);
    run_stats(z3, bg3 + k * 121, bb3 + k * 121, op_z3);

    hA = z3;  hAsc = SCp(op_z3);  hAsh = SHp(op_z3);
    hB = idn; hBsc = SCp(op_idn); hBsh = SHp(op_idn);
  }

  head_kernel<<<256, 256, 0, stream>>>(hA, hAsc, hAsh, hB, hBsc, hBsh,
                                       headW, (float*)d_out);
}

// Round 6
// 3006.742 us; speedup vs baseline: 1.3901x; 1.3901x over previous
//
#include <hip/hip_runtime.h>

#define NPOS 65536   // 64 batches * 32 * 32 positions
#define NE   121     // 11*11 tensor entries
#define NP   6       // p-rows per half for split kernels (P0 = ph*5; row 5 dup)

// ------------------------------------------------------------------
// f0: 8-channel 3x3 tensorized conv, 16x16 -> 11x11, writes raw y.
// Grid: 4096 = (b,h) x 2 p-halves; swizzle keeps a row's two halves and
// h-neighbors on one XCD. Block: 256 thr = (c, w).
// R1-R5 lesson: VGPR budget = 256/waves_per_eu; (256,2) caps at 128 and
// the load-pipeline slack pushes past it -> residual spill (WRITE 3.5GB).
// (256,1) raises the cap to 256; live ~150 incl. pipelining -> no spill.
// ------------------------------------------------------------------
__global__ __launch_bounds__(256, 1)
void f0_kernel(const float* __restrict__ x, const float* __restrict__ U,
               const float* __restrict__ V, float* __restrict__ y) {
  __shared__ float smem[2816];                // su(768)+sv(1408); reduce reuses 2816
  int bid = blockIdx.x;
  int wg  = (bid & 7) * 512 + (bid >> 3);     // bijective, 4096 % 8 == 0
  int ph  = wg & 1;                           // p-half; mate is 8 bids away (same XCD)
  int row = wg >> 1;                          // (b,h)
  int b = row >> 5, h = row & 31;
  int P0 = ph * 5;
  int t = threadIdx.x;
  int c = t >> 5, w = t & 31;

  float* su = smem;           // [c][pr][m] : c*96 + pr*16 + m   (768)
  float* sv = smem + 768;     // [c][q][n]  : c*176 + q*16 + n   (1408)

  float Y[NP][11];
#pragma unroll
  for (int p = 0; p < NP; ++p)
#pragma unroll
    for (int q = 0; q < 11; ++q) Y[p][q] = 0.f;

  for (int ij = 0; ij < 9; ++ij) {
    __syncthreads();
    for (int idx = t; idx < 768; idx += 256) {
      int cc = idx / 96, r = idx - cc * 96;
      int pr = r >> 4, m = r & 15;
      su[idx] = U[(cc * 9 + ij) * 176 + (P0 + pr) * 16 + m];
    }
    for (int idx = t; idx < 1408; idx += 256) {
      int cc = idx / 176, qn = idx - cc * 176;
      sv[idx] = V[(cc * 9 + ij) * 176 + qn];
    }
    __syncthreads();
    int i = ij / 3, j = ij - 3 * (ij / 3);
    int hi = h + i - 1, wj = w + j - 1;
    if ((unsigned)hi < 32u && (unsigned)wj < 32u) {
      const float* xb = x + ((size_t)(b * 8 + c) << 18) + (hi << 5) + wj;
      const float* uB = &su[c * 96];
      const float* vB = &sv[c * 176];
      for (int nc = 0; nc < 4; ++nc) {        // n in chunks of 4
        float A[NP][4];
#pragma unroll
        for (int p = 0; p < NP; ++p)
#pragma unroll
          for (int k = 0; k < 4; ++k) A[p][k] = 0.f;
#pragma unroll 2
        for (int m = 0; m < 16; ++m) {
          float Xr[4];
#pragma unroll
          for (int k = 0; k < 4; ++k)
            Xr[k] = xb[(m * 16 + nc * 4 + k) << 10];
#pragma unroll
          for (int p = 0; p < NP; ++p) {
            float u = uB[p * 16 + m];
#pragma unroll
            for (int k = 0; k < 4; ++k) A[p][k] += u * Xr[k];
          }
        }
#pragma unroll
        for (int k = 0; k < 4; ++k) {
#pragma unroll
          for (int q = 0; q < 11; ++q) {
            float vv = vB[q * 16 + nc * 4 + k];
#pragma unroll
            for (int p = 0; p < NP; ++p) Y[p][q] += A[p][k] * vv;
          }
        }
      }
    }
  }

  // reduce over c (8 threads per (w,q)) through LDS, one p-row at a time
  int posb = ((b << 5) + h) << 5;
#pragma unroll
  for (int p = 0; p < NP; ++p) {
    __syncthreads();
#pragma unroll
    for (int q = 0; q < 11; ++q) smem[(c * 32 + w) * 11 + q] = Y[p][q];
    __syncthreads();
    for (int idx = t; idx < 352; idx += 256) {
      int qq = idx >> 5, w2 = idx & 31;
      float s = 0.f;
#pragma unroll
      for (int cc = 0; cc < 8; ++cc) s += smem[(cc * 32 + w2) * 11 + qq];
      y[(size_t)((P0 + p) * 11 + qq) * NPOS + posb + w2] = s;
    }
  }
}

// ------------------------------------------------------------------
// TBN stats: partial sums (484 blocks), then finalize scale/shift.
// ------------------------------------------------------------------
__global__ __launch_bounds__(256)
void stats_partial(const float* __restrict__ raw, float* __restrict__ part) {
  int blk = blockIdx.x;
  int e = blk >> 2, qt = blk & 3;
  const float4* p = (const float4*)(raw + (size_t)e * NPOS) + qt * 4096;
  int t = threadIdx.x;
  float s = 0.f, s2 = 0.f;
  for (int i = t; i < 4096; i += 256) {
    float4 v = p[i];
    s  += v.x + v.y + v.z + v.w;
    s2 += v.x * v.x + v.y * v.y + v.z * v.z + v.w * v.w;
  }
#pragma unroll
  for (int o = 32; o > 0; o >>= 1) {
    s  += __shfl_down(s, o);
    s2 += __shfl_down(s2, o);
  }
  __shared__ float ls[8];
  int wid = t >> 6;
  if ((t & 63) == 0) { ls[wid] = s; ls[4 + wid] = s2; }
  __syncthreads();
  if (t == 0) {
    part[blk]       = ls[0] + ls[1] + ls[2] + ls[3];
    part[484 + blk] = ls[4] + ls[5] + ls[6] + ls[7];
  }
}

__global__ void stats_final(const float* __restrict__ part, const float* __restrict__ g,
                            const float* __restrict__ bb, float* __restrict__ sc,
                            float* __restrict__ sh) {
  int e = threadIdx.x;
  if (e < 121) {
    float s  = part[e * 4] + part[e * 4 + 1] + part[e * 4 + 2] + part[e * 4 + 3];
    float s2 = part[484 + e * 4] + part[484 + e * 4 + 1] +
               part[484 + e * 4 + 2] + part[484 + e * 4 + 3];
    float mu  = s  * (1.f / 65536.f);
    float var = s2 * (1.f / 65536.f) - mu * mu;
    float sca = g[e] * rsqrtf(var + 1e-5f);
    sc[e] = sca;
    sh[e] = bb[e] - mu * sca;
  }
}

// ------------------------------------------------------------------
// tconv1x1: out_raw = U * hin * V^T per position, 2-way p-split.
// hin = affine(A) [+ affine(B)] [then PReLU(alpha)], applied on load.
// Grid: 512 = 256 pos-blocks x 2 halves. ~90 live regs -> fits 128.
// ------------------------------------------------------------------
template<bool HASB, bool PRELU>
__global__ __launch_bounds__(256, 2)
void conv1x1_kernel(const float* __restrict__ rA, const float* __restrict__ scA,
                    const float* __restrict__ shA,
                    const float* __restrict__ rB, const float* __restrict__ scB,
                    const float* __restrict__ shB,
                    const float* __restrict__ alpha_ptr, int alpha_idx,
                    const float* __restrict__ U, const float* __restrict__ V,
                    float* __restrict__ out) {
  __shared__ float su[NP * 11], sv[121], sa[242], sb[242];
  int bid = blockIdx.x;
  int wg  = (bid & 7) * 64 + (bid >> 3);      // 512 % 8 == 0, bijective
  int ph = wg & 1, posblk = wg >> 1;
  int P0 = ph * 5;
  int t = threadIdx.x;
  if (t < 121) {
    sv[t] = V[t];
    sa[t] = scA[t]; sb[t] = shA[t];
    if (HASB) { sa[121 + t] = scB[t]; sb[121 + t] = shB[t]; }
  }
  if (t < NP * 11) su[t] = U[P0 * 11 + t];    // su[pr*11+m] = U[(P0+pr)*11+m]
  __syncthreads();
  float alpha = 0.f;
  if (PRELU) alpha = alpha_ptr[alpha_idx];
  size_t pos = (size_t)posblk * 256 + t;

  float T[NP][11];
#pragma unroll
  for (int p = 0; p < NP; ++p)
#pragma unroll
    for (int n = 0; n < 11; ++n) T[p][n] = 0.f;

#pragma unroll 2
  for (int m = 0; m < 11; ++m) {
    float Xr[11];
#pragma unroll
    for (int n = 0; n < 11; ++n) {
      int e = m * 11 + n;
      float v = sa[e] * rA[(size_t)e * NPOS + pos] + sb[e];
      if (HASB) v += sa[121 + e] * rB[(size_t)e * NPOS + pos] + sb[121 + e];
      if (PRELU) v = v >= 0.f ? v : alpha * v;
      Xr[n] = v;
    }
#pragma unroll
    for (int p = 0; p < NP; ++p) {
      float u = su[p * 11 + m];
#pragma unroll
      for (int n = 0; n < 11; ++n) T[p][n] += u * Xr[n];
    }
  }
#pragma unroll
  for (int q = 0; q < 11; ++q) {
    float Yc[NP];
#pragma unroll
    for (int p = 0; p < NP; ++p) Yc[p] = 0.f;
#pragma unroll
    for (int n = 0; n < 11; ++n) {
      float v = sv[q * 11 + n];
#pragma unroll
      for (int p = 0; p < NP; ++p) Yc[p] += T[p][n] * v;
    }
#pragma unroll
    for (int p = 0; p < NP; ++p)
      out[(size_t)((P0 + p) * 11 + q) * NPOS + pos] = Yc[p];
  }
}

// ------------------------------------------------------------------
// tconv3x3, 2-way p-split. Grid: 512 = 256 pos-blocks x 2 halves.
// Y[6][11]=66 + T[6][4]=24 + Xr4 ≈ 105 live -> fits 128.
// ------------------------------------------------------------------
template<int N0, int NW>
__device__ __forceinline__ void c3_chunk(const float* __restrict__ rA,
    const float* __restrict__ sa, const float* __restrict__ sh,
    const float* __restrict__ su, const float* __restrict__ sv,
    float alpha, int npos, float (&Y)[NP][11]) {
  float T[NP][NW];
#pragma unroll
  for (int p = 0; p < NP; ++p)
#pragma unroll
    for (int k = 0; k < NW; ++k) T[p][k] = 0.f;
#pragma unroll 2
  for (int m = 0; m < 11; ++m) {
    float Xr[NW];
#pragma unroll
    for (int k = 0; k < NW; ++k) {
      int e = m * 11 + N0 + k;
      float v = sa[e] * rA[(size_t)e * NPOS + npos] + sh[e];
      Xr[k] = v >= 0.f ? v : alpha * v;
    }
#pragma unroll
    for (int p = 0; p < NP; ++p) {
      float u = su[p * 11 + m];
#pragma unroll
      for (int k = 0; k < NW; ++k) T[p][k] += u * Xr[k];
    }
  }
#pragma unroll
  for (int k = 0; k < NW; ++k) {
#pragma unroll
    for (int q = 0; q < 11; ++q) {
      float v = sv[q * 11 + N0 + k];
#pragma unroll
      for (int p = 0; p < NP; ++p) Y[p][q] += T[p][k] * v;
    }
  }
}

__global__ __launch_bounds__(256, 2)
void conv3x3_kernel(const float* __restrict__ rA, const float* __restrict__ scA,
                    const float* __restrict__ shA,
                    const float* __restrict__ alpha_ptr, int alpha_idx,
                    const float* __restrict__ U, const float* __restrict__ V,
                    float* __restrict__ out) {
  __shared__ float su[9 * NP * 11], sv[1089], sa[121], sh[121];
  int bid = blockIdx.x;
  int wg  = (bid & 7) * 64 + (bid >> 3);
  int ph = wg & 1, posblk = wg >> 1;
  int P0 = ph * 5;
  int t = threadIdx.x;
  for (int idx = t; idx < 9 * NP * 11; idx += 256) {
    int ij = idx / (NP * 11), r = idx - ij * (NP * 11);   // r = pr*11+m
    su[idx] = U[ij * 121 + P0 * 11 + r];
  }
  for (int idx = t; idx < 1089; idx += 256) sv[idx] = V[idx];
  if (t < 121) { sa[t] = scA[t]; sh[t] = shA[t]; }
  __syncthreads();
  float alpha = alpha_ptr[alpha_idx];
  int pos = posblk * 256 + t;
  int b = pos >> 10, h = (pos >> 5) & 31, w = pos & 31;

  float Y[NP][11];
#pragma unroll
  for (int p = 0; p < NP; ++p)
#pragma unroll
    for (int q = 0; q < 11; ++q) Y[p][q] = 0.f;

  for (int ij = 0; ij < 9; ++ij) {
    int i = ij / 3, j = ij - 3 * (ij / 3);
    int hi = h + i - 1, wj = w + j - 1;
    if ((unsigned)hi >= 32u || (unsigned)wj >= 32u) continue;  // zero pad: tap = 0
    int npos = ((b << 5) + hi) * 32 + wj;
    const float* suij = &su[ij * NP * 11];
    const float* svij = &sv[ij * 121];
    c3_chunk<0, 4>(rA, sa, sh, suij, svij, alpha, npos, Y);
    c3_chunk<4, 4>(rA, sa, sh, suij, svij, alpha, npos, Y);
    c3_chunk<8, 3>(rA, sa, sh, suij, svij, alpha, npos, Y);
  }
#pragma unroll
  for (int p = 0; p < NP; ++p)
#pragma unroll
    for (int q = 0; q < 11; ++q)
      out[(size_t)((P0 + p) * 11 + q) * NPOS + pos] = Y[p][q];
}

// ------------------------------------------------------------------
// fcn head: out[b,o,h,w] = sum_e h[e]*W[o,e]; h = affine(A)+affine(B).
// ------------------------------------------------------------------
__global__ __launch_bounds__(256, 2)
void head_kernel(const float* __restrict__ rA, const float* __restrict__ scA,
                 const float* __restrict__ shA,
                 const float* __restrict__ rB, const float* __restrict__ scB,
                 const float* __restrict__ shB,
                 const float* __restrict__ W, float* __restrict__ out) {
  __shared__ float sw[21 * 121], sa[242], sh[242];
  int t = threadIdx.x;
  for (int idx = t; idx < 2541; idx += 256) sw[idx] = W[idx];
  if (t < 121) {
    sa[t] = scA[t]; sh[t] = shA[t];
    sa[121 + t] = scB[t]; sh[121 + t] = shB[t];
  }
  __syncthreads();
  size_t pos = (size_t)blockIdx.x * 256 + t;
  int b = (int)(pos >> 10), hw = (int)(pos & 1023);
  float acc[21];
#pragma unroll
  for (int o = 0; o < 21; ++o) acc[o] = 0.f;
  for (int e = 0; e < 121; ++e) {
    float v = sa[e] * rA[(size_t)e * NPOS + pos] + sh[e] +
              sa[121 + e] * rB[(size_t)e * NPOS + pos] + sh[121 + e];
#pragma unroll
    for (int o = 0; o < 21; ++o) acc[o] += v * sw[o * 121 + e];
  }
#pragma unroll
  for (int o = 0; o < 21; ++o)
    out[(size_t)(b * 21 + o) * 1024 + hw] = acc[o];
}

// ------------------------------------------------------------------
extern "C" void kernel_launch(void* const* d_in, const int* in_sizes, int n_in,
                              void* d_out, int out_size, void* d_ws, size_t ws_size,
                              hipStream_t stream) {
  (void)in_sizes; (void)n_in; (void)out_size; (void)ws_size;
  const float* x     = (const float*)d_in[0];
  const float* f0_U  = (const float*)d_in[1];
  const float* f0_V  = (const float*)d_in[2];
  const float* f0_g  = (const float*)d_in[3];
  const float* f0_b  = (const float*)d_in[4];
  const float* f0_a  = (const float*)d_in[5];
  const float* s_U   = (const float*)d_in[6];
  const float* s_V   = (const float*)d_in[7];
  const float* s_g   = (const float*)d_in[8];
  const float* s_b   = (const float*)d_in[9];
  const float* bU1   = (const float*)d_in[10];
  const float* bV1   = (const float*)d_in[11];
  const float* bg1   = (const float*)d_in[12];
  const float* bb1   = (const float*)d_in[13];
  const float* ba1   = (const float*)d_in[14];
  const float* bU2   = (const float*)d_in[15];
  const float* bV2   = (const float*)d_in[16];
  const float* bg2   = (const float*)d_in[17];
  const float* bb2   = (const float*)d_in[18];
  const float* ba2   = (const float*)d_in[19];
  const float* bU3   = (const float*)d_in[20];
  const float* bV3   = (const float*)d_in[21];
  const float* bg3   = (const float*)d_in[22];
  const float* bb3   = (const float*)d_in[23];
  const float* headW = (const float*)d_in[24];

  float* ws = (float*)d_ws;
  const size_t BUF = (size_t)NE * NPOS;           // 7,929,856 floats per buffer
  float* B[4] = { ws, ws + BUF, ws + 2 * BUF, ws + 3 * BUF };
  float* st   = ws + 4 * BUF;                     // 17 ops * (scale121 + shift121)
  float* part = st + 17 * 242;                    // 968 floats of partial sums

  auto SCp = [&](int op) { return st + op * 242; };
  auto SHp = [&](int op) { return st + op * 242 + 121; };
  auto run_stats = [&](const float* raw, const float* g, const float* bb, int op) {
    stats_partial<<<484, 256, 0, stream>>>(raw, part);
    stats_final<<<1, 128, 0, stream>>>(part, g, bb, SCp(op), SHp(op));
  };

  // ---- f0 ----
  f0_kernel<<<4096, 256, 0, stream>>>(x, f0_U, f0_V, B[0]);
  run_stats(B[0], f0_g, f0_b, 0);

  // buffer rotation: for each block k -> {idn, z1, z2, z3} buffer index
  const int bufs[4][4] = { {1,2,3,0}, {2,3,0,1}, {3,0,1,2}, {0,1,2,3} };

  const float* hA   = B[0];  const float* hAsc = SCp(0); const float* hAsh = SHp(0);
  const float* hB   = nullptr; const float* hBsc = nullptr; const float* hBsh = nullptr;

  for (int k = 0; k < 4; ++k) {
    float* idn = B[bufs[k][0]];
    float* z1  = B[bufs[k][1]];
    float* z2  = B[bufs[k][2]];
    float* z3  = B[bufs[k][3]];
    int op_idn = 1 + k * 4, op_z1 = 2 + k * 4, op_z2 = 3 + k * 4, op_z3 = 4 + k * 4;

    if (k == 0) {  // h0 = prelu(tbn(y), f0_a): single source + prelu
      conv1x1_kernel<false, true><<<512, 256, 0, stream>>>(
          hA, hAsc, hAsh, nullptr, nullptr, nullptr, f0_a, 0,
          s_U + k * 121, s_V + k * 121, idn);
      conv1x1_kernel<false, true><<<512, 256, 0, stream>>>(
          hA, hAsc, hAsh, nullptr, nullptr, nullptr, f0_a, 0,
          bU1 + k * 121, bV1 + k * 121, z1);
    } else {       // h = tbn(z3_prev) + tbn(idn_prev): two sources, no prelu
      conv1x1_kernel<true, false><<<512, 256, 0, stream>>>(
          hA, hAsc, hAsh, hB, hBsc, hBsh, nullptr, 0,
          s_U + k * 121, s_V + k * 121, idn);
      conv1x1_kernel<true, false><<<512, 256, 0, stream>>>(
          hA, hAsc, hAsh, hB, hBsc, hBsh, nullptr, 0,
          bU1 + k * 121, bV1 + k * 121, z1);
    }
    run_stats(idn, s_g + k * 121, s_b + k * 121, op_idn);
    run_stats(z1,  bg1 + k * 121, bb1 + k * 121, op_z1);

    conv3x3_kernel<<<512, 256, 0, stream>>>(
        z1, SCp(op_z1), SHp(op_z1), ba1, k,
        bU2 + k * 1089, bV2 + k * 1089, z2);
    run_stats(z2, bg2 + k * 121, bb2 + k * 121, op_z2);

    conv1x1_kernel<false, true><<<512, 256, 0, stream>>>(
        z2, SCp(op_z2), SHp(op_z2), nullptr, nullptr, nullptr, ba2, k,
        bU3 + k * 121, bV3 + k * 121, z3);
    run_stats(z3, bg3 + k * 121, bb3 + k * 121, op_z3);

    hA = z3;  hAsc = SCp(op_z3);  hAsh = SHp(op_z3);
    hB = idn; hBsc = SCp(op_idn); hBsh = SHp(op_idn);
  }

  head_kernel<<<256, 256, 0, stream>>>(hA, hAsc, hAsh, hB, hBsc, hBsh,
                                       headW, (float*)d_out);
}

// Round 7
// 2007.793 us; speedup vs baseline: 2.0818x; 1.4975x over previous
//
#include <hip/hip_runtime.h>

#define NPOS 65536   // 64 batches * 32 * 32 positions
#define NE   121     // 11*11 tensor entries
#define NP   6       // p-rows per half for split kernels (P0 = ph*5; row 5 dup)

// ------------------------------------------------------------------
// f0: 8-channel 3x3 tensorized conv, 16x16 -> 11x11, writes raw y.
// R6 lesson: spill fixed via (256,1), but inner loop was global-load
// latency-bound (VALUBusy 25%). Now: X tile (32KB, one (c,hi) slab)
// lives in LDS; inner loop is pure LDS+FMA. Threads = (s,w): s owns
// n in {2s,2s+1}; Y[11][11] partial per thread, reduced over s at end.
// T14 async staging: next tile -> 8 float4 regs during compute,
// ds_write after barrier. U/V staged transposed per c (broadcast b128).
// ------------------------------------------------------------------
__global__ __launch_bounds__(256, 1)
void f0_kernel(const float* __restrict__ x, const float* __restrict__ U,
               const float* __restrict__ V, float* __restrict__ y) {
  __shared__ float Xl[8192];    // [m][n][w] flat: (m*16+n)*32 + w   (32KB)
  __shared__ float UTl[1728];   // [tap][m][p(pad12)]
  __shared__ float VTl[1728];   // [tap][n][q(pad12)]

  int bid = blockIdx.x;
  int wg  = (bid & 7) * 256 + (bid >> 3);     // XCD swizzle, 2048 % 8 == 0
  int b = wg >> 5, h = wg & 31;
  int t = threadIdx.x;
  int s = t >> 5, w = t & 31;                 // s = n-slice, w = column

  float Y[11][11];
#pragma unroll
  for (int p = 0; p < 11; ++p)
#pragma unroll
    for (int q = 0; q < 11; ++q) Y[p][q] = 0.f;

  const int ii0 = (h == 0) ? 1 : 0;
  const int ii1 = (h == 31) ? 2 : 3;

  float4 pf[8];
  // issue global loads for tile (c,hi) into pf regs (coalesced float4)
  auto issueX = [&](int c, int hi) {
    const float* base = x + ((size_t)(b * 8 + c) << 18) + hi * 32;
#pragma unroll
    for (int k = 0; k < 8; ++k) {
      int ff = k * 256 + t;                   // float4 index 0..2047
      int mn = ff >> 3, w4 = ff & 7;
      pf[k] = *reinterpret_cast<const float4*>(base + (size_t)mn * 1024 + w4 * 4);
    }
  };
  auto writeX = [&]() {
#pragma unroll
    for (int k = 0; k < 8; ++k)
      reinterpret_cast<float4*>(Xl)[k * 256 + t] = pf[k];
  };

  issueX(0, h - 1 + ii0);

  for (int c = 0; c < 8; ++c) {
    __syncthreads();                          // prev c done with UTl/VTl
    // stage U,V transposed for this c: UT[tap][m][p12], VT[tap][n][q12]
    for (int idx = t; idx < 1728; idx += 256) {
      int tap = idx / 192, r = idx - tap * 192;
      int m = r / 12, pp = r - m * 12;
      float uu = 0.f, vv = 0.f;
      if (pp < 11) {
        uu = U[(c * 9 + tap) * 176 + pp * 16 + m];
        vv = V[(c * 9 + tap) * 176 + pp * 16 + m];
      }
      UTl[idx] = uu; VTl[idx] = vv;
    }
    for (int ii = ii0; ii < ii1; ++ii) {
      __syncthreads();                        // everyone done with prev X tile
      writeX();                               // ds_write current tile
      int cn = c, iin = ii + 1;               // prefetch next tile
      if (iin == ii1) { cn = c + 1; iin = ii0; }
      if (cn < 8) issueX(cn, h - 1 + iin);
      __syncthreads();                        // X (and UV) visible

      // compute: taps (i=ii, j=0..2) against this tile
#pragma unroll
      for (int j = 0; j < 3; ++j) {
        int wj = w + j - 1;
        if ((unsigned)wj < 32u) {
          int tap = ii * 3 + j;
          const float* UT = &UTl[tap * 192];
          const float* VT = &VTl[tap * 192];
          float A[11][2];
#pragma unroll
          for (int p = 0; p < 11; ++p) { A[p][0] = 0.f; A[p][1] = 0.f; }
#pragma unroll 4
          for (int m = 0; m < 16; ++m) {
            float x0 = Xl[(m * 16 + 2 * s) * 32 + wj];
            float x1 = Xl[(m * 16 + 2 * s + 1) * 32 + wj];
            float4 u0 = *reinterpret_cast<const float4*>(&UT[m * 12 + 0]);
            float4 u1 = *reinterpret_cast<const float4*>(&UT[m * 12 + 4]);
            float4 u2 = *reinterpret_cast<const float4*>(&UT[m * 12 + 8]);
            float up[11] = { u0.x, u0.y, u0.z, u0.w,
                             u1.x, u1.y, u1.z, u1.w,
                             u2.x, u2.y, u2.z };
#pragma unroll
            for (int p = 0; p < 11; ++p) {
              A[p][0] += up[p] * x0;
              A[p][1] += up[p] * x1;
            }
          }
#pragma unroll
          for (int nn = 0; nn < 2; ++nn) {
            const float* vb = &VT[(2 * s + nn) * 12];
            float4 v0 = *reinterpret_cast<const float4*>(&vb[0]);
            float4 v1 = *reinterpret_cast<const float4*>(&vb[4]);
            float4 v2 = *reinterpret_cast<const float4*>(&vb[8]);
            float vq[11] = { v0.x, v0.y, v0.z, v0.w,
                             v1.x, v1.y, v1.z, v1.w,
                             v2.x, v2.y, v2.z };
#pragma unroll
            for (int p = 0; p < 11; ++p)
#pragma unroll
              for (int q = 0; q < 11; ++q)
                Y[p][q] += A[p][nn] * vq[q];
          }
        }
      }
    }
  }

  // reduce over s (8 partials per (w,p,q)) through LDS (reuse Xl)
  int posb = ((b << 5) + h) << 5;
#pragma unroll
  for (int p = 0; p < 11; ++p) {
    __syncthreads();
#pragma unroll
    for (int q = 0; q < 11; ++q) Xl[t * 11 + q] = Y[p][q];
    __syncthreads();
    for (int idx = t; idx < 352; idx += 256) {
      int qq = idx >> 5, w2 = idx & 31;
      float ssum = 0.f;
#pragma unroll
      for (int s2 = 0; s2 < 8; ++s2) ssum += Xl[(s2 * 32 + w2) * 11 + qq];
      y[(size_t)(p * 11 + qq) * NPOS + posb + w2] = ssum;
    }
  }
}

// ------------------------------------------------------------------
// TBN stats: partial sums (484 blocks), then finalize scale/shift.
// ------------------------------------------------------------------
__global__ __launch_bounds__(256)
void stats_partial(const float* __restrict__ raw, float* __restrict__ part) {
  int blk = blockIdx.x;
  int e = blk >> 2, qt = blk & 3;
  const float4* p = (const float4*)(raw + (size_t)e * NPOS) + qt * 4096;
  int t = threadIdx.x;
  float s = 0.f, s2 = 0.f;
  for (int i = t; i < 4096; i += 256) {
    float4 v = p[i];
    s  += v.x + v.y + v.z + v.w;
    s2 += v.x * v.x + v.y * v.y + v.z * v.z + v.w * v.w;
  }
#pragma unroll
  for (int o = 32; o > 0; o >>= 1) {
    s  += __shfl_down(s, o);
    s2 += __shfl_down(s2, o);
  }
  __shared__ float ls[8];
  int wid = t >> 6;
  if ((t & 63) == 0) { ls[wid] = s; ls[4 + wid] = s2; }
  __syncthreads();
  if (t == 0) {
    part[blk]       = ls[0] + ls[1] + ls[2] + ls[3];
    part[484 + blk] = ls[4] + ls[5] + ls[6] + ls[7];
  }
}

__global__ void stats_final(const float* __restrict__ part, const float* __restrict__ g,
                            const float* __restrict__ bb, float* __restrict__ sc,
                            float* __restrict__ sh) {
  int e = threadIdx.x;
  if (e < 121) {
    float s  = part[e * 4] + part[e * 4 + 1] + part[e * 4 + 2] + part[e * 4 + 3];
    float s2 = part[484 + e * 4] + part[484 + e * 4 + 1] +
               part[484 + e * 4 + 2] + part[484 + e * 4 + 3];
    float mu  = s  * (1.f / 65536.f);
    float var = s2 * (1.f / 65536.f) - mu * mu;
    float sca = g[e] * rsqrtf(var + 1e-5f);
    sc[e] = sca;
    sh[e] = bb[e] - mu * sca;
  }
}

// ------------------------------------------------------------------
// tconv1x1: out_raw = U * hin * V^T per position, 2-way p-split.
// hin = affine(A) [+ affine(B)] [then PReLU(alpha)], applied on load.
// ------------------------------------------------------------------
template<bool HASB, bool PRELU>
__global__ __launch_bounds__(256, 2)
void conv1x1_kernel(const float* __restrict__ rA, const float* __restrict__ scA,
                    const float* __restrict__ shA,
                    const float* __restrict__ rB, const float* __restrict__ scB,
                    const float* __restrict__ shB,
                    const float* __restrict__ alpha_ptr, int alpha_idx,
                    const float* __restrict__ U, const float* __restrict__ V,
                    float* __restrict__ out) {
  __shared__ float su[NP * 11], sv[121], sa[242], sb[242];
  int bid = blockIdx.x;
  int wg  = (bid & 7) * 64 + (bid >> 3);      // 512 % 8 == 0, bijective
  int ph = wg & 1, posblk = wg >> 1;
  int P0 = ph * 5;
  int t = threadIdx.x;
  if (t < 121) {
    sv[t] = V[t];
    sa[t] = scA[t]; sb[t] = shA[t];
    if (HASB) { sa[121 + t] = scB[t]; sb[121 + t] = shB[t]; }
  }
  if (t < NP * 11) su[t] = U[P0 * 11 + t];
  __syncthreads();
  float alpha = 0.f;
  if (PRELU) alpha = alpha_ptr[alpha_idx];
  size_t pos = (size_t)posblk * 256 + t;

  float T[NP][11];
#pragma unroll
  for (int p = 0; p < NP; ++p)
#pragma unroll
    for (int n = 0; n < 11; ++n) T[p][n] = 0.f;

#pragma unroll 2
  for (int m = 0; m < 11; ++m) {
    float Xr[11];
#pragma unroll
    for (int n = 0; n < 11; ++n) {
      int e = m * 11 + n;
      float v = sa[e] * rA[(size_t)e * NPOS + pos] + sb[e];
      if (HASB) v += sa[121 + e] * rB[(size_t)e * NPOS + pos] + sb[121 + e];
      if (PRELU) v = v >= 0.f ? v : alpha * v;
      Xr[n] = v;
    }
#pragma unroll
    for (int p = 0; p < NP; ++p) {
      float u = su[p * 11 + m];
#pragma unroll
      for (int n = 0; n < 11; ++n) T[p][n] += u * Xr[n];
    }
  }
#pragma unroll
  for (int q = 0; q < 11; ++q) {
    float Yc[NP];
#pragma unroll
    for (int p = 0; p < NP; ++p) Yc[p] = 0.f;
#pragma unroll
    for (int n = 0; n < 11; ++n) {
      float v = sv[q * 11 + n];
#pragma unroll
      for (int p = 0; p < NP; ++p) Yc[p] += T[p][n] * v;
    }
#pragma unroll
    for (int p = 0; p < NP; ++p)
      out[(size_t)((P0 + p) * 11 + q) * NPOS + pos] = Yc[p];
  }
}

// ------------------------------------------------------------------
// tconv3x3, 2-way p-split. Grid: 512 = 256 pos-blocks x 2 halves.
// ------------------------------------------------------------------
template<int N0, int NW>
__device__ __forceinline__ void c3_chunk(const float* __restrict__ rA,
    const float* __restrict__ sa, const float* __restrict__ sh,
    const float* __restrict__ su, const float* __restrict__ sv,
    float alpha, int npos, float (&Y)[NP][11]) {
  float T[NP][NW];
#pragma unroll
  for (int p = 0; p < NP; ++p)
#pragma unroll
    for (int k = 0; k < NW; ++k) T[p][k] = 0.f;
#pragma unroll 2
  for (int m = 0; m < 11; ++m) {
    float Xr[NW];
#pragma unroll
    for (int k = 0; k < NW; ++k) {
      int e = m * 11 + N0 + k;
      float v = sa[e] * rA[(size_t)e * NPOS + npos] + sh[e];
      Xr[k] = v >= 0.f ? v : alpha * v;
    }
#pragma unroll
    for (int p = 0; p < NP; ++p) {
      float u = su[p * 11 + m];
#pragma unroll
      for (int k = 0; k < NW; ++k) T[p][k] += u * Xr[k];
    }
  }
#pragma unroll
  for (int k = 0; k < NW; ++k) {
#pragma unroll
    for (int q = 0; q < 11; ++q) {
      float v = sv[q * 11 + N0 + k];
#pragma unroll
      for (int p = 0; p < NP; ++p) Y[p][q] += T[p][k] * v;
    }
  }
}

__global__ __launch_bounds__(256, 2)
void conv3x3_kernel(const float* __restrict__ rA, const float* __restrict__ scA,
                    const float* __restrict__ shA,
                    const float* __restrict__ alpha_ptr, int alpha_idx,
                    const float* __restrict__ U, const float* __restrict__ V,
                    float* __restrict__ out) {
  __shared__ float su[9 * NP * 11], sv[1089], sa[121], sh[121];
  int bid = blockIdx.x;
  int wg  = (bid & 7) * 64 + (bid >> 3);
  int ph = wg & 1, posblk = wg >> 1;
  int P0 = ph * 5;
  int t = threadIdx.x;
  for (int idx = t; idx < 9 * NP * 11; idx += 256) {
    int ij = idx / (NP * 11), r = idx - ij * (NP * 11);
    su[idx] = U[ij * 121 + P0 * 11 + r];
  }
  for (int idx = t; idx < 1089; idx += 256) sv[idx] = V[idx];
  if (t < 121) { sa[t] = scA[t]; sh[t] = shA[t]; }
  __syncthreads();
  float alpha = alpha_ptr[alpha_idx];
  int pos = posblk * 256 + t;
  int b = pos >> 10, h = (pos >> 5) & 31, w = pos & 31;

  float Y[NP][11];
#pragma unroll
  for (int p = 0; p < NP; ++p)
#pragma unroll
    for (int q = 0; q < 11; ++q) Y[p][q] = 0.f;

  for (int ij = 0; ij < 9; ++ij) {
    int i = ij / 3, j = ij - 3 * (ij / 3);
    int hi = h + i - 1, wj = w + j - 1;
    if ((unsigned)hi >= 32u || (unsigned)wj >= 32u) continue;
    int npos = ((b << 5) + hi) * 32 + wj;
    const float* suij = &su[ij * NP * 11];
    const float* svij = &sv[ij * 121];
    c3_chunk<0, 4>(rA, sa, sh, suij, svij, alpha, npos, Y);
    c3_chunk<4, 4>(rA, sa, sh, suij, svij, alpha, npos, Y);
    c3_chunk<8, 3>(rA, sa, sh, suij, svij, alpha, npos, Y);
  }
#pragma unroll
  for (int p = 0; p < NP; ++p)
#pragma unroll
    for (int q = 0; q < 11; ++q)
      out[(size_t)((P0 + p) * 11 + q) * NPOS + pos] = Y[p][q];
}

// ------------------------------------------------------------------
// fcn head: out[b,o,h,w] = sum_e h[e]*W[o,e]; h = affine(A)+affine(B).
// ------------------------------------------------------------------
__global__ __launch_bounds__(256, 2)
void head_kernel(const float* __restrict__ rA, const float* __restrict__ scA,
                 const float* __restrict__ shA,
                 const float* __restrict__ rB, const float* __restrict__ scB,
                 const float* __restrict__ shB,
                 const float* __restrict__ W, float* __restrict__ out) {
  __shared__ float sw[21 * 121], sa[242], sh[242];
  int t = threadIdx.x;
  for (int idx = t; idx < 2541; idx += 256) sw[idx] = W[idx];
  if (t < 121) {
    sa[t] = scA[t]; sh[t] = shA[t];
    sa[121 + t] = scB[t]; sh[121 + t] = shB[t];
  }
  __syncthreads();
  size_t pos = (size_t)blockIdx.x * 256 + t;
  int b = (int)(pos >> 10), hw = (int)(pos & 1023);
  float acc[21];
#pragma unroll
  for (int o = 0; o < 21; ++o) acc[o] = 0.f;
  for (int e = 0; e < 121; ++e) {
    float v = sa[e] * rA[(size_t)e * NPOS + pos] + sh[e] +
              sa[121 + e] * rB[(size_t)e * NPOS + pos] + sh[121 + e];
#pragma unroll
    for (int o = 0; o < 21; ++o) acc[o] += v * sw[o * 121 + e];
  }
#pragma unroll
  for (int o = 0; o < 21; ++o)
    out[(size_t)(b * 21 + o) * 1024 + hw] = acc[o];
}

// ------------------------------------------------------------------
extern "C" void kernel_launch(void* const* d_in, const int* in_sizes, int n_in,
                              void* d_out, int out_size, void* d_ws, size_t ws_size,
                              hipStream_t stream) {
  (void)in_sizes; (void)n_in; (void)out_size; (void)ws_size;
  const float* x     = (const float*)d_in[0];
  const float* f0_U  = (const float*)d_in[1];
  const float* f0_V  = (const float*)d_in[2];
  const float* f0_g  = (const float*)d_in[3];
  const float* f0_b  = (const float*)d_in[4];
  const float* f0_a  = (const float*)d_in[5];
  const float* s_U   = (const float*)d_in[6];
  const float* s_V   = (const float*)d_in[7];
  const float* s_g   = (const float*)d_in[8];
  const float* s_b   = (const float*)d_in[9];
  const float* bU1   = (const float*)d_in[10];
  const float* bV1   = (const float*)d_in[11];
  const float* bg1   = (const float*)d_in[12];
  const float* bb1   = (const float*)d_in[13];
  const float* ba1   = (const float*)d_in[14];
  const float* bU2   = (const float*)d_in[15];
  const float* bV2   = (const float*)d_in[16];
  const float* bg2   = (const float*)d_in[17];
  const float* bb2   = (const float*)d_in[18];
  const float* ba2   = (const float*)d_in[19];
  const float* bU3   = (const float*)d_in[20];
  const float* bV3   = (const float*)d_in[21];
  const float* bg3   = (const float*)d_in[22];
  const float* bb3   = (const float*)d_in[23];
  const float* headW = (const float*)d_in[24];

  float* ws = (float*)d_ws;
  const size_t BUF = (size_t)NE * NPOS;
  float* B[4] = { ws, ws + BUF, ws + 2 * BUF, ws + 3 * BUF };
  float* st   = ws + 4 * BUF;
  float* part = st + 17 * 242;

  auto SCp = [&](int op) { return st + op * 242; };
  auto SHp = [&](int op) { return st + op * 242 + 121; };
  auto run_stats = [&](const float* raw, const float* g, const float* bb, int op) {
    stats_partial<<<484, 256, 0, stream>>>(raw, part);
    stats_final<<<1, 128, 0, stream>>>(part, g, bb, SCp(op), SHp(op));
  };

  // ---- f0 ----
  f0_kernel<<<2048, 256, 0, stream>>>(x, f0_U, f0_V, B[0]);
  run_stats(B[0], f0_g, f0_b, 0);

  const int bufs[4][4] = { {1,2,3,0}, {2,3,0,1}, {3,0,1,2}, {0,1,2,3} };

  const float* hA   = B[0];  const float* hAsc = SCp(0); const float* hAsh = SHp(0);
  const float* hB   = nullptr; const float* hBsc = nullptr; const float* hBsh = nullptr;

  for (int k = 0; k < 4; ++k) {
    float* idn = B[bufs[k][0]];
    float* z1  = B[bufs[k][1]];
    float* z2  = B[bufs[k][2]];
    float* z3  = B[bufs[k][3]];
    int op_idn = 1 + k * 4, op_z1 = 2 + k * 4, op_z2 = 3 + k * 4, op_z3 = 4 + k * 4;

    if (k == 0) {
      conv1x1_kernel<false, true><<<512, 256, 0, stream>>>(
          hA, hAsc, hAsh, nullptr, nullptr, nullptr, f0_a, 0,
          s_U + k * 121, s_V + k * 121, idn);
      conv1x1_kernel<false, true><<<512, 256, 0, stream>>>(
          hA, hAsc, hAsh, nullptr, nullptr, nullptr, f0_a, 0,
          bU1 + k * 121, bV1 + k * 121, z1);
    } else {
      conv1x1_kernel<true, false><<<512, 256, 0, stream>>>(
          hA, hAsc, hAsh, hB, hBsc, hBsh, nullptr, 0,
          s_U + k * 121, s_V + k * 121, idn);
      conv1x1_kernel<true, false><<<512, 256, 0, stream>>>(
          hA, hAsc, hAsh, hB, hBsc, hBsh, nullptr, 0,
          bU1 + k * 121, bV1 + k * 121, z1);
    }
    run_stats(idn, s_g + k * 121, s_b + k * 121, op_idn);
    run_stats(z1,  bg1 + k * 121, bb1 + k * 121, op_z1);

    conv3x3_kernel<<<512, 256, 0, stream>>>(
        z1, SCp(op_z1), SHp(op_z1), ba1, k,
        bU2 + k * 1089, bV2 + k * 1089, z2);
    run_stats(z2, bg2 + k * 121, bb2 + k * 121, op_z2);

    conv1x1_kernel<false, true><<<512, 256, 0, stream>>>(
        z2, SCp(op_z2), SHp(op_z2), nullptr, nullptr, nullptr, ba2, k,
        bU3 + k * 121, bV3 + k * 121, z3);
    run_stats(z3, bg3 + k * 121, bb3 + k * 121, op_z3);

    hA = z3;  hAsc = SCp(op_z3);  hAsh = SHp(op_z3);
    hB = idn; hBsc = SCp(op_idn); hBsh = SHp(op_idn);
  }

  head_kernel<<<256, 256, 0, stream>>>(hA, hAsc, hAsh, hB, hBsc, hBsh,
                                       headW, (float*)d_out);
}

// Round 8
// 1872.522 us; speedup vs baseline: 2.2322x; 1.0722x over previous
//
#include <hip/hip_runtime.h>

#define NPOS 65536   // 64 batches * 32 * 32 positions
#define NE   121     // 11*11 tensor entries
#define NP   6       // p-rows per half (P0 = ph*5; row 5 dup)

// direct HBM->LDS (no VGPR staging; dest = wave-uniform base + lane*16)
__device__ __forceinline__ void gload_lds16(const float* g, float* l) {
  __builtin_amdgcn_global_load_lds(
      (const __attribute__((address_space(1))) void*)g,
      (__attribute__((address_space(3))) void*)l, 16, 0, 0);
}

// ------------------------------------------------------------------
// f0: 8-channel 3x3 tensorized conv, 16x16 -> 11x11, writes raw y.
// Grid 4096 = (b,h) x 2 p-halves (XCD-swizzled mates). 256 thr = (s,w):
// s owns n in {2s,2s+1}, p rows P0..P0+5. X slab [16m][16n][32w] (32KB)
// double-buffered in LDS via global_load_lds (R7 lesson: reg-staged
// prefetch = 32 VGPRs -> scratch, 1.4GB WRITE). Live ~110 VGPR.
// Loop: [barrier(drains slab k) ; issue slab k+1 ; compute slab k].
// ------------------------------------------------------------------
__global__ __launch_bounds__(256, 1)
void f0_kernel(const float* __restrict__ x, const float* __restrict__ U,
               const float* __restrict__ V, float* __restrict__ y) {
  __shared__ float Xb[16384];   // 2 x 8192 (64KB)
  __shared__ float su[1152];    // [tap][m][8]  : p-rows P0..P0+5 (+2 pad)
  __shared__ float sv[1728];    // [tap][n][12] : q 0..10 (+1 pad)

  int bid = blockIdx.x;
  int wg  = (bid & 7) * 512 + (bid >> 3);     // bijective, 4096 % 8 == 0
  int ph  = wg & 1;
  int row = wg >> 1;
  int b = row >> 5, h = row & 31;
  int P0 = ph * 5;
  int t = threadIdx.x;
  int s = t >> 5, w = t & 31;

  int hlo = (h == 0) ? 0 : h - 1;
  int hhi = (h == 31) ? 31 : h + 1;
  int nh = hhi - hlo + 1;
  int nslab = 8 * nh;

  float Y[NP][11];
#pragma unroll
  for (int p = 0; p < NP; ++p)
#pragma unroll
    for (int q = 0; q < 11; ++q) Y[p][q] = 0.f;

  // stage U,V for channel c into padded broadcast layouts
  auto stageUV = [&](int c) {
    for (int idx = t; idx < 1152; idx += 256) {     // su[tap*128 + m*8 + pr]
      int tap = idx >> 7, r = idx & 127;
      int m = r >> 3, pr = r & 7;
      su[idx] = (pr < 6) ? U[(c * 9 + tap) * 176 + (P0 + pr) * 16 + m] : 0.f;
    }
    for (int idx = t; idx < 1728; idx += 256) {     // sv[tap*192 + n*12 + q]
      int tap = idx / 192, r = idx - tap * 192;
      int n = r / 12, q = r - n * 12;
      sv[idx] = (q < 11) ? V[(c * 9 + tap) * 176 + q * 16 + n] : 0.f;
    }
  };

  // async-issue slab (c,hi) into LDS buffer (8192 floats, 32KB)
  auto issueX = [&](int k) {
    int c = k / nh, hi = hlo + k % nh;
    const float* base = x + ((size_t)(b * 8 + c) << 18) + hi * 32;
    float* buf = &Xb[(k & 1) * 8192];
    int wv = t >> 6, lane = t & 63;
#pragma unroll
    for (int kk = 0; kk < 8; ++kk) {
      int chunk = wv * 8 + kk;                      // 0..31, wave-uniform
      int mn = chunk * 8 + (lane >> 3);             // 0..255
      gload_lds16(base + (size_t)mn * 1024 + (lane & 7) * 4,
                  buf + chunk * 256);
    }
  };

  stageUV(0);
  issueX(0);

  for (int k = 0; k < nslab; ++k) {
    asm volatile("s_waitcnt vmcnt(0)" ::: "memory"); // slab k landed
    __syncthreads();                                 // all waves: LDS ready
    if (k + 1 < nslab) issueX(k + 1);                // async prefetch

    const float* Xt = &Xb[(k & 1) * 8192];
    int c = k / nh, hi = hlo + k % nh;
    int tapbase = (hi - h + 1) * 3;
#pragma unroll
    for (int j = 0; j < 3; ++j) {
      int wj = w + j - 1;
      if ((unsigned)wj < 32u) {
        int tap = tapbase + j;
        const float* suT = &su[tap * 128];
        const float* svT = &sv[tap * 192];
        float A0[6], A1[6];
#pragma unroll
        for (int p = 0; p < 6; ++p) { A0[p] = 0.f; A1[p] = 0.f; }
#pragma unroll
        for (int m = 0; m < 16; ++m) {
          float x0 = Xt[(m * 16 + 2 * s) * 32 + wj];
          float x1 = Xt[(m * 16 + 2 * s + 1) * 32 + wj];
          float4 u0 = *(const float4*)&suT[m * 8];       // broadcast
          float2 u1 = *(const float2*)&suT[m * 8 + 4];
          A0[0] += u0.x * x0; A1[0] += u0.x * x1;
          A0[1] += u0.y * x0; A1[1] += u0.y * x1;
          A0[2] += u0.z * x0; A1[2] += u0.z * x1;
          A0[3] += u0.w * x0; A1[3] += u0.w * x1;
          A0[4] += u1.x * x0; A1[4] += u1.x * x1;
          A0[5] += u1.y * x0; A1[5] += u1.y * x1;
        }
#pragma unroll
        for (int nn = 0; nn < 2; ++nn) {
          const float* vb = &svT[(2 * s + nn) * 12];
          float4 v0 = *(const float4*)&vb[0];
          float4 v1 = *(const float4*)&vb[4];
          float4 v2 = *(const float4*)&vb[8];
          float vq[11] = { v0.x, v0.y, v0.z, v0.w,
                           v1.x, v1.y, v1.z, v1.w,
                           v2.x, v2.y, v2.z };
          const float* Ax = nn ? A1 : A0;    // nn is unroll-static
#pragma unroll
          for (int p = 0; p < 6; ++p)
#pragma unroll
            for (int q = 0; q < 11; ++q)
              Y[p][q] += Ax[p] * vq[q];
        }
      }
    }
    // new channel next slab: re-stage UV after everyone finished this c
    if (k + 1 < nslab && (k % nh) == nh - 1) {
      __syncthreads();
      stageUV(c + 1);
    }
  }

  // reduce over s (8 partials per (w,p,q)) through LDS (reuse Xb)
  int posb = ((b << 5) + h) << 5;
#pragma unroll
  for (int p = 0; p < NP; ++p) {
    __syncthreads();
#pragma unroll
    for (int q = 0; q < 11; ++q) Xb[t * 11 + q] = Y[p][q];
    __syncthreads();
    for (int idx = t; idx < 352; idx += 256) {
      int qq = idx >> 5, w2 = idx & 31;
      float ssum = 0.f;
#pragma unroll
      for (int s2 = 0; s2 < 8; ++s2) ssum += Xb[(s2 * 32 + w2) * 11 + qq];
      y[(size_t)((P0 + p) * 11 + qq) * NPOS + posb + w2] = ssum;
    }
  }
}

// ------------------------------------------------------------------
// TBN stats: ONE kernel, 121 blocks (one per entry): full reduce over
// 65536 values + finalize scale/shift. Deterministic tree.
// ------------------------------------------------------------------
__global__ __launch_bounds__(256)
void stats_kernel(const float* __restrict__ raw, const float* __restrict__ g,
                  const float* __restrict__ bb, float* __restrict__ sc,
                  float* __restrict__ sh) {
  int e = blockIdx.x;
  const float4* p = (const float4*)(raw + (size_t)e * NPOS);
  int t = threadIdx.x;
  float s = 0.f, s2 = 0.f;
  for (int i = t; i < 16384; i += 256) {
    float4 v = p[i];
    s  += v.x + v.y + v.z + v.w;
    s2 += v.x * v.x + v.y * v.y + v.z * v.z + v.w * v.w;
  }
#pragma unroll
  for (int o = 32; o > 0; o >>= 1) {
    s  += __shfl_down(s, o);
    s2 += __shfl_down(s2, o);
  }
  __shared__ float ls[8];
  int wid = t >> 6;
  if ((t & 63) == 0) { ls[wid] = s; ls[4 + wid] = s2; }
  __syncthreads();
  if (t == 0) {
    float ss  = ls[0] + ls[1] + ls[2] + ls[3];
    float ss2 = ls[4] + ls[5] + ls[6] + ls[7];
    float mu  = ss  * (1.f / 65536.f);
    float var = ss2 * (1.f / 65536.f) - mu * mu;
    float sca = g[e] * rsqrtf(var + 1e-5f);
    sc[e] = sca;
    sh[e] = bb[e] - mu * sca;
  }
}

// ------------------------------------------------------------------
// tconv1x1: out_raw = U * hin * V^T per position, 2-way p-split.
// ------------------------------------------------------------------
template<bool HASB, bool PRELU>
__global__ __launch_bounds__(256, 2)
void conv1x1_kernel(const float* __restrict__ rA, const float* __restrict__ scA,
                    const float* __restrict__ shA,
                    const float* __restrict__ rB, const float* __restrict__ scB,
                    const float* __restrict__ shB,
                    const float* __restrict__ alpha_ptr, int alpha_idx,
                    const float* __restrict__ U, const float* __restrict__ V,
                    float* __restrict__ out) {
  __shared__ float su[NP * 11], sv[121], sa[242], sb[242];
  int bid = blockIdx.x;
  int wg  = (bid & 7) * 64 + (bid >> 3);
  int ph = wg & 1, posblk = wg >> 1;
  int P0 = ph * 5;
  int t = threadIdx.x;
  if (t < 121) {
    sv[t] = V[t];
    sa[t] = scA[t]; sb[t] = shA[t];
    if (HASB) { sa[121 + t] = scB[t]; sb[121 + t] = shB[t]; }
  }
  if (t < NP * 11) su[t] = U[P0 * 11 + t];
  __syncthreads();
  float alpha = 0.f;
  if (PRELU) alpha = alpha_ptr[alpha_idx];
  size_t pos = (size_t)posblk * 256 + t;

  float T[NP][11];
#pragma unroll
  for (int p = 0; p < NP; ++p)
#pragma unroll
    for (int n = 0; n < 11; ++n) T[p][n] = 0.f;

#pragma unroll 2
  for (int m = 0; m < 11; ++m) {
    float Xr[11];
#pragma unroll
    for (int n = 0; n < 11; ++n) {
      int e = m * 11 + n;
      float v = sa[e] * rA[(size_t)e * NPOS + pos] + sb[e];
      if (HASB) v += sa[121 + e] * rB[(size_t)e * NPOS + pos] + sb[121 + e];
      if (PRELU) v = v >= 0.f ? v : alpha * v;
      Xr[n] = v;
    }
#pragma unroll
    for (int p = 0; p < NP; ++p) {
      float u = su[p * 11 + m];
#pragma unroll
      for (int n = 0; n < 11; ++n) T[p][n] += u * Xr[n];
    }
  }
#pragma unroll
  for (int q = 0; q < 11; ++q) {
    float Yc[NP];
#pragma unroll
    for (int p = 0; p < NP; ++p) Yc[p] = 0.f;
#pragma unroll
    for (int n = 0; n < 11; ++n) {
      float v = sv[q * 11 + n];
#pragma unroll
      for (int p = 0; p < NP; ++p) Yc[p] += T[p][n] * v;
    }
#pragma unroll
    for (int p = 0; p < NP; ++p)
      out[(size_t)((P0 + p) * 11 + q) * NPOS + pos] = Yc[p];
  }
}

// ------------------------------------------------------------------
// tconv3x3, 2-way p-split.
// ------------------------------------------------------------------
template<int N0, int NW>
__device__ __forceinline__ void c3_chunk(const float* __restrict__ rA,
    const float* __restrict__ sa, const float* __restrict__ sh,
    const float* __restrict__ su, const float* __restrict__ sv,
    float alpha, int npos, float (&Y)[NP][11]) {
  float T[NP][NW];
#pragma unroll
  for (int p = 0; p < NP; ++p)
#pragma unroll
    for (int k = 0; k < NW; ++k) T[p][k] = 0.f;
#pragma unroll 2
  for (int m = 0; m < 11; ++m) {
    float Xr[NW];
#pragma unroll
    for (int k = 0; k < NW; ++k) {
      int e = m * 11 + N0 + k;
      float v = sa[e] * rA[(size_t)e * NPOS + npos] + sh[e];
      Xr[k] = v >= 0.f ? v : alpha * v;
    }
#pragma unroll
    for (int p = 0; p < NP; ++p) {
      float u = su[p * 11 + m];
#pragma unroll
      for (int k = 0; k < NW; ++k) T[p][k] += u * Xr[k];
    }
  }
#pragma unroll
  for (int k = 0; k < NW; ++k) {
#pragma unroll
    for (int q = 0; q < 11; ++q) {
      float v = sv[q * 11 + N0 + k];
#pragma unroll
      for (int p = 0; p < NP; ++p) Y[p][q] += T[p][k] * v;
    }
  }
}

__global__ __launch_bounds__(256, 2)
void conv3x3_kernel(const float* __restrict__ rA, const float* __restrict__ scA,
                    const float* __restrict__ shA,
                    const float* __restrict__ alpha_ptr, int alpha_idx,
                    const float* __restrict__ U, const float* __restrict__ V,
                    float* __restrict__ out) {
  __shared__ float su[9 * NP * 11], sv[1089], sa[121], sh[121];
  int bid = blockIdx.x;
  int wg  = (bid & 7) * 64 + (bid >> 3);
  int ph = wg & 1, posblk = wg >> 1;
  int P0 = ph * 5;
  int t = threadIdx.x;
  for (int idx = t; idx < 9 * NP * 11; idx += 256) {
    int ij = idx / (NP * 11), r = idx - ij * (NP * 11);
    su[idx] = U[ij * 121 + P0 * 11 + r];
  }
  for (int idx = t; idx < 1089; idx += 256) sv[idx] = V[idx];
  if (t < 121) { sa[t] = scA[t]; sh[t] = shA[t]; }
  __syncthreads();
  float alpha = alpha_ptr[alpha_idx];
  int pos = posblk * 256 + t;
  int b = pos >> 10, h = (pos >> 5) & 31, w = pos & 31;

  float Y[NP][11];
#pragma unroll
  for (int p = 0; p < NP; ++p)
#pragma unroll
    for (int q = 0; q < 11; ++q) Y[p][q] = 0.f;

  for (int ij = 0; ij < 9; ++ij) {
    int i = ij / 3, j = ij - 3 * (ij / 3);
    int hi = h + i - 1, wj = w + j - 1;
    if ((unsigned)hi >= 32u || (unsigned)wj >= 32u) continue;
    int npos = ((b << 5) + hi) * 32 + wj;
    const float* suij = &su[ij * NP * 11];
    const float* svij = &sv[ij * 121];
    c3_chunk<0, 4>(rA, sa, sh, suij, svij, alpha, npos, Y);
    c3_chunk<4, 4>(rA, sa, sh, suij, svij, alpha, npos, Y);
    c3_chunk<8, 3>(rA, sa, sh, suij, svij, alpha, npos, Y);
  }
#pragma unroll
  for (int p = 0; p < NP; ++p)
#pragma unroll
    for (int q = 0; q < 11; ++q)
      out[(size_t)((P0 + p) * 11 + q) * NPOS + pos] = Y[p][q];
}

// ------------------------------------------------------------------
// fcn head
// ------------------------------------------------------------------
__global__ __launch_bounds__(256, 2)
void head_kernel(const float* __restrict__ rA, const float* __restrict__ scA,
                 const float* __restrict__ shA,
                 const float* __restrict__ rB, const float* __restrict__ scB,
                 const float* __restrict__ shB,
                 const float* __restrict__ W, float* __restrict__ out) {
  __shared__ float sw[21 * 121], sa[242], sh[242];
  int t = threadIdx.x;
  for (int idx = t; idx < 2541; idx += 256) sw[idx] = W[idx];
  if (t < 121) {
    sa[t] = scA[t]; sh[t] = shA[t];
    sa[121 + t] = scB[t]; sh[121 + t] = shB[t];
  }
  __syncthreads();
  size_t pos = (size_t)blockIdx.x * 256 + t;
  int b = (int)(pos >> 10), hw = (int)(pos & 1023);
  float acc[21];
#pragma unroll
  for (int o = 0; o < 21; ++o) acc[o] = 0.f;
  for (int e = 0; e < 121; ++e) {
    float v = sa[e] * rA[(size_t)e * NPOS + pos] + sh[e] +
              sa[121 + e] * rB[(size_t)e * NPOS + pos] + sh[121 + e];
#pragma unroll
    for (int o = 0; o < 21; ++o) acc[o] += v * sw[o * 121 + e];
  }
#pragma unroll
  for (int o = 0; o < 21; ++o)
    out[(size_t)(b * 21 + o) * 1024 + hw] = acc[o];
}

// ------------------------------------------------------------------
extern "C" void kernel_launch(void* const* d_in, const int* in_sizes, int n_in,
                              void* d_out, int out_size, void* d_ws, size_t ws_size,
                              hipStream_t stream) {
  (void)in_sizes; (void)n_in; (void)out_size; (void)ws_size;
  const float* x     = (const float*)d_in[0];
  const float* f0_U  = (const float*)d_in[1];
  const float* f0_V  = (const float*)d_in[2];
  const float* f0_g  = (const float*)d_in[3];
  const float* f0_b  = (const float*)d_in[4];
  const float* f0_a  = (const float*)d_in[5];
  const float* s_U   = (const float*)d_in[6];
  const float* s_V   = (const float*)d_in[7];
  const float* s_g   = (const float*)d_in[8];
  const float* s_b   = (const float*)d_in[9];
  const float* bU1   = (const float*)d_in[10];
  const float* bV1   = (const float*)d_in[11];
  const float* bg1   = (const float*)d_in[12];
  const float* bb1   = (const float*)d_in[13];
  const float* ba1   = (const float*)d_in[14];
  const float* bU2   = (const float*)d_in[15];
  const float* bV2   = (const float*)d_in[16];
  const float* bg2   = (const float*)d_in[17];
  const float* bb2   = (const float*)d_in[18];
  const float* ba2   = (const float*)d_in[19];
  const float* bU3   = (const float*)d_in[20];
  const float* bV3   = (const float*)d_in[21];
  const float* bg3   = (const float*)d_in[22];
  const float* bb3   = (const float*)d_in[23];
  const float* headW = (const float*)d_in[24];

  float* ws = (float*)d_ws;
  const size_t BUF = (size_t)NE * NPOS;
  float* B[4] = { ws, ws + BUF, ws + 2 * BUF, ws + 3 * BUF };
  float* st   = ws + 4 * BUF;               // 17 ops * (scale121 + shift121)

  auto SCp = [&](int op) { return st + op * 242; };
  auto SHp = [&](int op) { return st + op * 242 + 121; };
  auto run_stats = [&](const float* raw, const float* g, const float* bb, int op) {
    stats_kernel<<<121, 256, 0, stream>>>(raw, g, bb, SCp(op), SHp(op));
  };

  // ---- f0 ----
  f0_kernel<<<4096, 256, 0, stream>>>(x, f0_U, f0_V, B[0]);
  run_stats(B[0], f0_g, f0_b, 0);

  const int bufs[4][4] = { {1,2,3,0}, {2,3,0,1}, {3,0,1,2}, {0,1,2,3} };

  const float* hA   = B[0];  const float* hAsc = SCp(0); const float* hAsh = SHp(0);
  const float* hB   = nullptr; const float* hBsc = nullptr; const float* hBsh = nullptr;

  for (int k = 0; k < 4; ++k) {
    float* idn = B[bufs[k][0]];
    float* z1  = B[bufs[k][1]];
    float* z2  = B[bufs[k][2]];
    float* z3  = B[bufs[k][3]];
    int op_idn = 1 + k * 4, op_z1 = 2 + k * 4, op_z2 = 3 + k * 4, op_z3 = 4 + k * 4;

    if (k == 0) {
      conv1x1_kernel<false, true><<<512, 256, 0, stream>>>(
          hA, hAsc, hAsh, nullptr, nullptr, nullptr, f0_a, 0,
          s_U + k * 121, s_V + k * 121, idn);
      conv1x1_kernel<false, true><<<512, 256, 0, stream>>>(
          hA, hAsc, hAsh, nullptr, nullptr, nullptr, f0_a, 0,
          bU1 + k * 121, bV1 + k * 121, z1);
    } else {
      conv1x1_kernel<true, false><<<512, 256, 0, stream>>>(
          hA, hAsc, hAsh, hB, hBsc, hBsh, nullptr, 0,
          s_U + k * 121, s_V + k * 121, idn);
      conv1x1_kernel<true, false><<<512, 256, 0, stream>>>(
          hA, hAsc, hAsh, hB, hBsc, hBsh, nullptr, 0,
          bU1 + k * 121, bV1 + k * 121, z1);
    }
    run_stats(idn, s_g + k * 121, s_b + k * 121, op_idn);
    run_stats(z1,  bg1 + k * 121, bb1 + k * 121, op_z1);

    conv3x3_kernel<<<512, 256, 0, stream>>>(
        z1, SCp(op_z1), SHp(op_z1), ba1, k,
        bU2 + k * 1089, bV2 + k * 1089, z2);
    run_stats(z2, bg2 + k * 121, bb2 + k * 121, op_z2);

    conv1x1_kernel<false, true><<<512, 256, 0, stream>>>(
        z2, SCp(op_z2), SHp(op_z2), nullptr, nullptr, nullptr, ba2, k,
        bU3 + k * 121, bV3 + k * 121, z3);
    run_stats(z3, bg3 + k * 121, bb3 + k * 121, op_z3);

    hA = z3;  hAsc = SCp(op_z3);  hAsh = SHp(op_z3);
    hB = idn; hBsc = SCp(op_idn); hBsh = SHp(op_idn);
  }

  head_kernel<<<256, 256, 0, stream>>>(hA, hAsc, hAsh, hB, hBsc, hBsh,
                                       headW, (float*)d_out);
}